// Round 3
// baseline (152.312 us; speedup 1.0000x reference)
//
#include <hip/hip_runtime.h>

#define B_ 32
#define M_ 4096
#define M1_ 4097
#define H_ 32
#define D_ 4096

typedef float float4_ __attribute__((ext_vector_type(4)));
typedef float f32x4 __attribute__((ext_vector_type(4)));
typedef short short8 __attribute__((ext_vector_type(8)));
typedef short short4_ __attribute__((ext_vector_type(4)));

#define KOFF 131072
#define VOFF 16912384

// ws layout (f32-word offsets)
#define Q_OFF     0u            // 34*32*128 = 139264
#define O_OFF     139264u       // 32*32*128 = 131072
#define YPART_OFF 270336u       // 8*131072  = 1048576
#define QPART_OFF 1318912u      // 32*139264 = 4456448 (dead after k_reduce_q)
#define APO_OFF   1318912u      // u16: 32*64*32*128 = 8388608 u16 = 4194304 words (reuses qpart)
#define MSUM_OFF  5775360u      // 32*64*32*2 = 131072  -> total 5906432 f32 = 23.6 MB

__device__ __forceinline__ unsigned short f2bf(float f) {
  union { float f; unsigned u; } cv; cv.f = f;
  return (unsigned short)((cv.u + 0x7FFFu + ((cv.u >> 16) & 1u)) >> 16);
}
__device__ __forceinline__ float bf2f(unsigned short b) {
  union { unsigned u; float f; } cv; cv.u = ((unsigned)b) << 16;
  return cv.f;
}
__device__ __forceinline__ short8 pack8(const float* t) {
  short8 r;
#pragma unroll
  for (int j = 0; j < 8; ++j) r[j] = (short)f2bf(t[j]);
  return r;
}
__device__ __forceinline__ short8 load8cvt(const float* __restrict__ p) {
  float t[8];
  float4_ v0 = *(const float4_*)p;
  float4_ v1 = *(const float4_*)(p + 4);
#pragma unroll
  for (int j = 0; j < 4; ++j) { t[j] = v0[j]; t[4 + j] = v1[j]; }
  return pack8(t);
}

// ---------------- kernel 1: projections (q per head, k_new, v_new), split-D partials
// grid = 34 "heads" * 32 d-chunks = 1088 blocks. W double-buffered through LDS with
// next-chunk global loads issued BEFORE the barrier (prefetch pipeline).
__global__ __launch_bounds__(256, 4) void k_proj(const float* __restrict__ x,
    const float* __restrict__ Pq, const float* __restrict__ Pk,
    const float* __restrict__ Pv, float* __restrict__ qpart)
{
  __shared__ unsigned short Wl[2][32][128];
  int bid = blockIdx.x;
  int hh = bid >> 5;
  int c  = bid & 31;
  const float* W = (hh < 32) ? (Pq + (size_t)hh * D_ * 128)
                             : ((hh == 32) ? Pk : Pv);
  int d0 = c * 128;
  int tid = threadIdx.x;
  int w = tid >> 6, l = tid & 63, l15 = l & 15, lg = l >> 4;
  int sdr = tid >> 5, sk4 = (tid & 31) * 4;   // staging coords (row, col*4)
  f32x4 acc[2][2] = {};          // [b-tile][n-tile]
  float4_ tmp[4];
#pragma unroll
  for (int i = 0; i < 4; ++i)
    tmp[i] = *(const float4_*)(W + (size_t)(d0 + (i * 8 + sdr)) * 128 + sk4);
  for (int ks = 0; ks < 4; ++ks) {
    int buf = ks & 1;
#pragma unroll
    for (int i = 0; i < 4; ++i) {
      short4_ s;
#pragma unroll
      for (int j = 0; j < 4; ++j) s[j] = (short)f2bf(tmp[i][j]);
      *(short4_*)&Wl[buf][i * 8 + sdr][sk4] = s;
    }
    if (ks < 3) {
#pragma unroll
      for (int i = 0; i < 4; ++i)
        tmp[i] = *(const float4_*)(W + (size_t)(d0 + (ks + 1) * 32 + i * 8 + sdr) * 128 + sk4);
    }
    __syncthreads();
    int dk = d0 + ks * 32 + lg * 8;
    short8 af[2];
#pragma unroll
    for (int bt = 0; bt < 2; ++bt)
      af[bt] = load8cvt(x + (size_t)(bt * 16 + l15) * D_ + dk);
    short8 bf[2];
#pragma unroll
    for (int nti = 0; nti < 2; ++nti) {
      int col = (2 * w + nti) * 16 + l15;
      short8 t;
#pragma unroll
      for (int j = 0; j < 8; ++j) t[j] = (short)Wl[buf][lg * 8 + j][col];
      bf[nti] = t;
    }
#pragma unroll
    for (int bt = 0; bt < 2; ++bt)
#pragma unroll
      for (int nti = 0; nti < 2; ++nti)
        acc[bt][nti] = __builtin_amdgcn_mfma_f32_16x16x32_bf16(af[bt], bf[nti], acc[bt][nti], 0, 0, 0);
  }
#pragma unroll
  for (int bt = 0; bt < 2; ++bt)
#pragma unroll
    for (int nti = 0; nti < 2; ++nti) {
      int k = (2 * w + nti) * 16 + l15;
#pragma unroll
      for (int i = 0; i < 4; ++i) {
        int b = bt * 16 + lg * 4 + i;
        qpart[(size_t)((c * 34 + hh) * 32 + b) * 128 + k] = acc[bt][nti][i];
      }
    }
}

// ---------------- kernel 2: reduce projection partials; write new K/V cache row
__global__ __launch_bounds__(256) void k_reduce_q(const float* __restrict__ qpart,
    float* __restrict__ q, float* __restrict__ dout)
{
  int idx = blockIdx.x * 256 + threadIdx.x;   // 34*32*128 = 139264
  if (idx >= 34 * 32 * 128) return;
  float s = 0.f;
#pragma unroll
  for (int cc = 0; cc < 32; ++cc) s += qpart[(size_t)cc * 139264 + idx];
  q[idx] = s;
  int hh = idx >> 12;
  if (hh >= 32) {
    int b = (idx >> 7) & 31, k = idx & 127;
    size_t off = (hh == 32) ? (size_t)KOFF : (size_t)VOFF;
    dout[off + ((size_t)b * M1_ + M_) * 128 + k] = s;
  }
}

// ---------------- kernel 3: fused cache copy + flash-attention partials
// grid = B * 64 chunks of 64 rows = 2048 blocks, 256 threads.
__global__ __launch_bounds__(256, 4) void k_attn(const float* __restrict__ Kp,
    const float* __restrict__ Vp, const float* __restrict__ q,
    float* __restrict__ dout, unsigned short* __restrict__ apo,
    float* __restrict__ msum)
{
  __shared__ unsigned short Vl[64][128];   // V tile bf16, natural layout
  __shared__ float S[32][73];              // logits (odd stride vs bank conflicts)
  __shared__ unsigned short P[32][64];     // softmax probs bf16, XOR-swizzled
  __shared__ float smax[32], ssum[32], sextra[32];
  int bid = blockIdx.x;
  int b = bid >> 6, c = bid & 63;
  int m0 = c * 64;
  int tid = threadIdx.x, w = tid >> 6, l = tid & 63, l15 = l & 15, lg = l >> 4;
  const float* Kt = Kp + ((size_t)b * M_ + m0) * 128;
  const float* Vt = Vp + ((size_t)b * M_ + m0) * 128;
  float* Kn = dout + KOFF + ((size_t)b * M1_ + m0) * 128;
  float* Vn = dout + VOFF + ((size_t)b * M1_ + m0) * 128;

  // phase A: issue ALL 16 loads, THEN stores — sched_barrier stops the compiler
  // from sinking loads between stores (round-2 failure: VGPR=44 => 2 in flight).
  float4_ kr[8], vr[8];
#pragma unroll
  for (int i = 0; i < 8; ++i) kr[i] = ((const float4_*)Kt)[tid + i * 256];
#pragma unroll
  for (int i = 0; i < 8; ++i) vr[i] = ((const float4_*)Vt)[tid + i * 256];
  __builtin_amdgcn_sched_barrier(0);
#pragma unroll
  for (int i = 0; i < 8; ++i) ((float4_*)Kn)[tid + i * 256] = kr[i];
#pragma unroll
  for (int i = 0; i < 8; ++i) {
    int idx = tid + i * 256;
    ((float4_*)Vn)[idx] = vr[i];
    int m = idx >> 5, v = (idx & 31) * 4;
    short4_ s;
#pragma unroll
    for (int j = 0; j < 4; ++j) s[j] = (short)f2bf(vr[i][j]);
    *(short4_*)&Vl[m][v] = s;
  }

  // phase B: S[h][m] = q . K^T  (K frags re-read from L2-warm global)
  f32x4 sacc[2] = {};
#pragma unroll
  for (int ks = 0; ks < 4; ++ks) {
    short8 bfK = load8cvt(Kt + (size_t)(w * 16 + l15) * 128 + ks * 32 + lg * 8);
#pragma unroll
    for (int ht = 0; ht < 2; ++ht) {
      short8 af = load8cvt(q + (size_t)((ht * 16 + l15) * 32 + b) * 128 + ks * 32 + lg * 8);
      sacc[ht] = __builtin_amdgcn_mfma_f32_16x16x32_bf16(af, bfK, sacc[ht], 0, 0, 0);
    }
  }
#pragma unroll
  for (int ht = 0; ht < 2; ++ht)
#pragma unroll
    for (int i = 0; i < 4; ++i)
      S[ht * 16 + lg * 4 + i][w * 16 + l15] = sacc[ht][i];

  // appended-token logit (exact f32), last chunk only
  if (c == 63 && tid < 32) {
    int h = tid;
    const float* qh = q + (size_t)(h * 32 + b) * 128;
    const float* kn = q + (size_t)(32 * 32 + b) * 128;
    float s = 0.f;
    for (int k = 0; k < 128; ++k) s += qh[k] * kn[k];
    S[h][64] = s;
  }
  __syncthreads();

  // phase C: per-head partial softmax (8 lanes per head, 8 m each)
  {
    int h = tid >> 3, i = tid & 7;
    float vals[8];
    float mx = -3e38f;
#pragma unroll
    for (int j = 0; j < 8; ++j) { vals[j] = S[h][i * 8 + j]; mx = fmaxf(mx, vals[j]); }
#pragma unroll
    for (int d = 1; d < 8; d <<= 1) mx = fmaxf(mx, __shfl_xor(mx, d));
    if (c == 63) mx = fmaxf(mx, S[h][64]);
    float se = 0.f;
    short8 pw;
#pragma unroll
    for (int j = 0; j < 8; ++j) {
      float p = __expf(vals[j] - mx);
      se += p;
      pw[j] = (short)f2bf(p);
    }
    *(short8*)((char*)P + h * 128 + ((i * 16) ^ ((h & 7) << 4))) = pw;
    if (c == 63 && i == 0) { float pe = __expf(S[h][64] - mx); se += pe; sextra[h] = pe; }
#pragma unroll
    for (int d = 1; d < 8; d <<= 1) se += __shfl_xor(se, d);
    if (i == 0) { smax[h] = mx; ssum[h] = se; }
  }
  __syncthreads();

  // phase E: O[h][v] = P x V (P b128-swizzled from LDS, V u16 from LDS)
  f32x4 oacc[2][2] = {};   // [ht][vti]
#pragma unroll
  for (int ksv = 0; ksv < 2; ++ksv) {
    short8 af[2];
#pragma unroll
    for (int ht = 0; ht < 2; ++ht) {
      int h = ht * 16 + l15;
      af[ht] = *(const short8*)((const char*)P + h * 128 + ((ksv * 64 + lg * 16) ^ ((h & 7) << 4)));
    }
    short8 bf[2];
#pragma unroll
    for (int vti = 0; vti < 2; ++vti) {
      int v = w * 32 + vti * 16 + l15;
      short8 t;
#pragma unroll
      for (int j = 0; j < 8; ++j) t[j] = (short)Vl[ksv * 32 + lg * 8 + j][v];
      bf[vti] = t;
    }
#pragma unroll
    for (int ht = 0; ht < 2; ++ht)
#pragma unroll
      for (int vti = 0; vti < 2; ++vti)
        oacc[ht][vti] = __builtin_amdgcn_mfma_f32_16x16x32_bf16(af[ht], bf[vti], oacc[ht][vti], 0, 0, 0);
  }

  // phase F: write per-chunk partials (bf16 o, f32 max/sumexp)
  const float* vnew = q + (size_t)(33 * 32 + b) * 128;
#pragma unroll
  for (int ht = 0; ht < 2; ++ht)
#pragma unroll
    for (int vti = 0; vti < 2; ++vti) {
      int v = w * 32 + vti * 16 + l15;
#pragma unroll
      for (int i = 0; i < 4; ++i) {
        int h = ht * 16 + lg * 4 + i;
        float val = oacc[ht][vti][i];
        if (c == 63) val += sextra[h] * vnew[v];
        apo[((size_t)(b * 64 + c) * 32 + h) * 128 + v] = f2bf(val);
      }
    }
  if (tid < 32) {
    size_t base = ((size_t)(b * 64 + c) * 32 + tid) * 2;
    msum[base]     = smax[tid];
    msum[base + 1] = ssum[tid];
  }
}

// ---------------- kernel 4: combine chunk partials -> o[b][h][v]
__global__ void k_combine(const unsigned short* __restrict__ apo,
    const float* __restrict__ msum, float* __restrict__ o)
{
  int bid = blockIdx.x;            // 1024: b*32+h
  int b = bid >> 5, h = bid & 31;
  int v = threadIdx.x;             // 128
  float gm = -3e38f;
  for (int cc = 0; cc < 64; ++cc)
    gm = fmaxf(gm, msum[((size_t)(b * 64 + cc) * 32 + h) * 2]);
  float num = 0.f, den = 0.f;
  for (int cc = 0; cc < 64; ++cc) {
    size_t slot = (size_t)(b * 64 + cc) * 32 + h;
    float sc = __expf(msum[slot * 2] - gm);
    num += sc * bf2f(apo[slot * 128 + v]);
    den += sc * msum[slot * 2 + 1];
  }
  o[((size_t)(b * 32 + h)) * 128 + v] = num / den;
}

// ---------------- kernel 5: y partials = o x P_o  (grid 512 = 64 d-tiles x 8 head-groups)
__global__ __launch_bounds__(256) void k_out(const float* __restrict__ o,
    const float* __restrict__ Po, float* __restrict__ ypart)
{
  int bid = blockIdx.x;
  int dt = bid >> 3, hg = bid & 7;
  int tid = threadIdx.x, w = tid >> 6, l = tid & 63, l15 = l & 15, lg = l >> 4;
  int d = dt * 64 + w * 16 + l15;
  f32x4 acc[2] = {};               // [b-tile]
  for (int hi = 0; hi < 4; ++hi) {
    int h = hg * 4 + hi;
#pragma unroll
    for (int ks = 0; ks < 4; ++ks) {
      short8 af[2];
#pragma unroll
      for (int bt = 0; bt < 2; ++bt)
        af[bt] = load8cvt(o + ((size_t)((bt * 16 + l15) * 32 + h)) * 128 + ks * 32 + lg * 8);
      short8 bf = load8cvt(Po + ((size_t)h * D_ + d) * 128 + ks * 32 + lg * 8);
#pragma unroll
      for (int bt = 0; bt < 2; ++bt)
        acc[bt] = __builtin_amdgcn_mfma_f32_16x16x32_bf16(af[bt], bf, acc[bt], 0, 0, 0);
    }
  }
#pragma unroll
  for (int bt = 0; bt < 2; ++bt)
#pragma unroll
    for (int i = 0; i < 4; ++i) {
      int b = bt * 16 + lg * 4 + i;
      ypart[((size_t)(hg * 32 + b)) * 4096 + d] = acc[bt][i];
    }
}

// ---------------- kernel 6: reduce y partials -> y
__global__ __launch_bounds__(256) void k_reduce_y(const float* __restrict__ ypart,
    float* __restrict__ dout)
{
  int idx = blockIdx.x * 256 + threadIdx.x;  // 131072
  float s = 0.f;
#pragma unroll
  for (int g = 0; g < 8; ++g) s += ypart[(size_t)g * 131072 + idx];
  dout[idx] = s;
}

extern "C" void kernel_launch(void* const* d_in, const int* in_sizes, int n_in,
                              void* d_out, int out_size, void* d_ws, size_t ws_size,
                              hipStream_t stream) {
  (void)in_sizes; (void)n_in; (void)out_size; (void)ws_size;
  const float* x  = (const float*)d_in[0];
  const float* Kp = (const float*)d_in[1];
  const float* Vp = (const float*)d_in[2];
  const float* Pq = (const float*)d_in[3];
  const float* Pk = (const float*)d_in[4];
  const float* Pv = (const float*)d_in[5];
  const float* Po = (const float*)d_in[6];
  float* out = (float*)d_out;
  float* ws  = (float*)d_ws;
  float* q     = ws + Q_OFF;
  float* o     = ws + O_OFF;
  float* ypart = ws + YPART_OFF;
  float* qpart = ws + QPART_OFF;
  unsigned short* apo = (unsigned short*)(ws + APO_OFF);
  float* msum  = ws + MSUM_OFF;

  hipLaunchKernelGGL(k_proj,     dim3(1088), dim3(256), 0, stream, x, Pq, Pk, Pv, qpart);
  hipLaunchKernelGGL(k_reduce_q, dim3(544),  dim3(256), 0, stream, qpart, q, out);
  hipLaunchKernelGGL(k_attn,     dim3(2048), dim3(256), 0, stream, Kp, Vp, q, out, apo, msum);
  hipLaunchKernelGGL(k_combine,  dim3(1024), dim3(128), 0, stream, apo, msum, o);
  hipLaunchKernelGGL(k_out,      dim3(512),  dim3(256), 0, stream, o, Po, ypart);
  hipLaunchKernelGGL(k_reduce_y, dim3(512),  dim3(256), 0, stream, ypart, out);
}

// Round 4
// 131.881 us; speedup vs baseline: 1.1549x; 1.1549x over previous
//
#include <hip/hip_runtime.h>

#define B_ 32
#define M_ 4096
#define M1_ 4097
#define H_ 32
#define D_ 4096

typedef float float4_ __attribute__((ext_vector_type(4)));
typedef float f32x4 __attribute__((ext_vector_type(4)));
typedef short short8 __attribute__((ext_vector_type(8)));
typedef short short4_ __attribute__((ext_vector_type(4)));

#define KOFF 131072
#define VOFF 16912384

// ws layout (f32-word offsets)
#define Q_OFF     0u            // 34*32*128 = 139264
#define O_OFF     139264u       // 32*32*128 = 131072
#define YPART_OFF 270336u       // 8*131072  = 1048576
#define QPART_OFF 1318912u      // 16*139264 = 2228224 (dead after k_reduce_q)
#define APO_OFF   1318912u      // u16: 32*64*32*128 = 8388608 u16 = 4194304 words (reuses qpart)
#define MSUM_OFF  5513216u      // 32*64*32*2 = 131072  -> total 5644288 f32 = 22.6 MB

__device__ __forceinline__ unsigned short f2bf(float f) {
  union { float f; unsigned u; } cv; cv.f = f;
  return (unsigned short)((cv.u + 0x7FFFu + ((cv.u >> 16) & 1u)) >> 16);
}
__device__ __forceinline__ float bf2f(unsigned short b) {
  union { unsigned u; float f; } cv; cv.u = ((unsigned)b) << 16;
  return cv.f;
}
__device__ __forceinline__ short8 pack8(const float* t) {
  short8 r;
#pragma unroll
  for (int j = 0; j < 8; ++j) r[j] = (short)f2bf(t[j]);
  return r;
}
__device__ __forceinline__ short8 load8cvt(const float* __restrict__ p) {
  float t[8];
  float4_ v0 = *(const float4_*)p;
  float4_ v1 = *(const float4_*)(p + 4);
#pragma unroll
  for (int j = 0; j < 4; ++j) { t[j] = v0[j]; t[4 + j] = v1[j]; }
  return pack8(t);
}

// ---------------- kernel 1: projections (q per head, k_new, v_new), split-D partials
// R1 version: direct strided W frag reads (full-line coverage across the block;
// LDS staging in R2/R3 was a regression). grid = 34 "heads" * 16 d-chunks.
__global__ __launch_bounds__(256) void k_proj(const float* __restrict__ x,
    const float* __restrict__ Pq, const float* __restrict__ Pk,
    const float* __restrict__ Pv, float* __restrict__ qpart)
{
  int bid = blockIdx.x;
  int hh = bid >> 4;
  int c  = bid & 15;
  const float* W = (hh < 32) ? (Pq + (size_t)hh * D_ * 128)
                             : ((hh == 32) ? Pk : Pv);
  int d0 = c * 256;
  int tid = threadIdx.x;
  int w = tid >> 6, l = tid & 63, l15 = l & 15, lg = l >> 4;
  f32x4 acc[2][2] = {};          // [b-tile][n-tile]
  for (int ks = 0; ks < 8; ++ks) {
    int dk = d0 + ks * 32 + lg * 8;
    short8 af[2];
#pragma unroll
    for (int bt = 0; bt < 2; ++bt)
      af[bt] = load8cvt(x + (size_t)(bt * 16 + l15) * D_ + dk);
    short8 bf[2];
#pragma unroll
    for (int nti = 0; nti < 2; ++nti) {
      int col = (2 * w + nti) * 16 + l15;
      float t[8];
#pragma unroll
      for (int j = 0; j < 8; ++j) t[j] = W[(size_t)(dk + j) * 128 + col];
      bf[nti] = pack8(t);
    }
#pragma unroll
    for (int bt = 0; bt < 2; ++bt)
#pragma unroll
      for (int nti = 0; nti < 2; ++nti)
        acc[bt][nti] = __builtin_amdgcn_mfma_f32_16x16x32_bf16(af[bt], bf[nti], acc[bt][nti], 0, 0, 0);
  }
#pragma unroll
  for (int bt = 0; bt < 2; ++bt)
#pragma unroll
    for (int nti = 0; nti < 2; ++nti) {
      int k = (2 * w + nti) * 16 + l15;
#pragma unroll
      for (int i = 0; i < 4; ++i) {
        int b = bt * 16 + lg * 4 + i;
        qpart[(size_t)((c * 34 + hh) * 32 + b) * 128 + k] = acc[bt][nti][i];
      }
    }
}

// ---------------- kernel 2: reduce projection partials; write new K/V cache row
__global__ __launch_bounds__(256) void k_reduce_q(const float* __restrict__ qpart,
    float* __restrict__ q, float* __restrict__ dout)
{
  int idx = blockIdx.x * 256 + threadIdx.x;   // 34*32*128 = 139264
  if (idx >= 34 * 32 * 128) return;
  float s = 0.f;
#pragma unroll
  for (int cc = 0; cc < 16; ++cc) s += qpart[(size_t)cc * 139264 + idx];
  q[idx] = s;
  int hh = idx >> 12;
  if (hh >= 32) {
    int b = (idx >> 7) & 31, k = idx & 127;
    size_t off = (hh == 32) ? (size_t)KOFF : (size_t)VOFF;
    dout[off + ((size_t)b * M1_ + M_) * 128 + k] = s;
  }
}

// ---------------- kernel 3: fused cache copy + flash-attention partials
// grid = B * 64 chunks of 64 rows = 2048 blocks, 256 threads.
// Slim LDS (~14 KB) + VGPR<=64 -> 8 blocks/CU so copy phases of some blocks
// overlap compute phases of others. Non-temporal stores for streaming writes.
__global__ __launch_bounds__(256, 8) void k_attn(const float* __restrict__ Kp,
    const float* __restrict__ Vp, const float* __restrict__ q,
    float* __restrict__ dout, unsigned short* __restrict__ apo,
    float* __restrict__ msum)
{
  __shared__ float S[32][73];              // logits (odd stride vs bank conflicts)
  __shared__ unsigned short P[32][64];     // softmax probs bf16, XOR-swizzled
  __shared__ float smax[32], ssum[32], sextra[32];
  int bid = blockIdx.x;
  int b = bid >> 6, c = bid & 63;
  int m0 = c * 64;
  int tid = threadIdx.x, w = tid >> 6, l = tid & 63, l15 = l & 15, lg = l >> 4;
  const float* Kt = Kp + ((size_t)b * M_ + m0) * 128;
  const float* Vt = Vp + ((size_t)b * M_ + m0) * 128;
  float* Kn = dout + KOFF + ((size_t)b * M1_ + m0) * 128;
  float* Vn = dout + VOFF + ((size_t)b * M1_ + m0) * 128;

  // phase A: copy (4-deep load batches, nontemporal streaming stores)
#pragma unroll
  for (int g = 0; g < 2; ++g) {
    float4_ t[4];
#pragma unroll
    for (int i = 0; i < 4; ++i) t[i] = ((const float4_*)Kt)[tid + (g * 4 + i) * 256];
    __builtin_amdgcn_sched_barrier(0);
#pragma unroll
    for (int i = 0; i < 4; ++i)
      __builtin_nontemporal_store(t[i], &((float4_*)Kn)[tid + (g * 4 + i) * 256]);
  }
#pragma unroll
  for (int g = 0; g < 2; ++g) {
    float4_ t[4];
#pragma unroll
    for (int i = 0; i < 4; ++i) t[i] = ((const float4_*)Vt)[tid + (g * 4 + i) * 256];
    __builtin_amdgcn_sched_barrier(0);
#pragma unroll
    for (int i = 0; i < 4; ++i)
      __builtin_nontemporal_store(t[i], &((float4_*)Vn)[tid + (g * 4 + i) * 256]);
  }

  // phase B: S[h][m] = q . K^T  (K frags re-read from L2-warm global)
  f32x4 sacc[2] = {};
#pragma unroll
  for (int ks = 0; ks < 4; ++ks) {
    short8 bfK = load8cvt(Kt + (size_t)(w * 16 + l15) * 128 + ks * 32 + lg * 8);
#pragma unroll
    for (int ht = 0; ht < 2; ++ht) {
      short8 af = load8cvt(q + (size_t)((ht * 16 + l15) * 32 + b) * 128 + ks * 32 + lg * 8);
      sacc[ht] = __builtin_amdgcn_mfma_f32_16x16x32_bf16(af, bfK, sacc[ht], 0, 0, 0);
    }
  }
#pragma unroll
  for (int ht = 0; ht < 2; ++ht)
#pragma unroll
    for (int i = 0; i < 4; ++i)
      S[ht * 16 + lg * 4 + i][w * 16 + l15] = sacc[ht][i];

  // appended-token logit (exact f32), last chunk only
  if (c == 63 && tid < 32) {
    int h = tid;
    const float* qh = q + (size_t)(h * 32 + b) * 128;
    const float* kn = q + (size_t)(32 * 32 + b) * 128;
    float s = 0.f;
    for (int k = 0; k < 128; ++k) s += qh[k] * kn[k];
    S[h][64] = s;
  }
  __syncthreads();

  // phase C: per-head partial softmax (8 lanes per head, 8 m each)
  {
    int h = tid >> 3, i = tid & 7;
    float vals[8];
    float mx = -3e38f;
#pragma unroll
    for (int j = 0; j < 8; ++j) { vals[j] = S[h][i * 8 + j]; mx = fmaxf(mx, vals[j]); }
#pragma unroll
    for (int d = 1; d < 8; d <<= 1) mx = fmaxf(mx, __shfl_xor(mx, d));
    if (c == 63) mx = fmaxf(mx, S[h][64]);
    float se = 0.f;
    short8 pw;
#pragma unroll
    for (int j = 0; j < 8; ++j) {
      float p = __expf(vals[j] - mx);
      se += p;
      pw[j] = (short)f2bf(p);
    }
    *(short8*)((char*)P + h * 128 + ((i * 16) ^ ((h & 7) << 4))) = pw;
    if (c == 63 && i == 0) { float pe = __expf(S[h][64] - mx); se += pe; sextra[h] = pe; }
#pragma unroll
    for (int d = 1; d < 8; d <<= 1) se += __shfl_xor(se, d);
    if (i == 0) { smax[h] = mx; ssum[h] = se; }
  }
  __syncthreads();

  // phase E: O[h][v] = P x V (P b128-swizzled from LDS, V frags from L2-warm global)
  f32x4 oacc[2][2] = {};   // [ht][vti]
#pragma unroll
  for (int ksv = 0; ksv < 2; ++ksv) {
    short8 af[2];
#pragma unroll
    for (int ht = 0; ht < 2; ++ht) {
      int h = ht * 16 + l15;
      af[ht] = *(const short8*)((const char*)P + h * 128 + ((ksv * 64 + lg * 16) ^ ((h & 7) << 4)));
    }
    short8 bf[2];
#pragma unroll
    for (int vti = 0; vti < 2; ++vti) {
      int v = w * 32 + vti * 16 + l15;
      float t[8];
#pragma unroll
      for (int j = 0; j < 8; ++j) t[j] = Vt[(size_t)(ksv * 32 + lg * 8 + j) * 128 + v];
      bf[vti] = pack8(t);
    }
#pragma unroll
    for (int ht = 0; ht < 2; ++ht)
#pragma unroll
      for (int vti = 0; vti < 2; ++vti)
        oacc[ht][vti] = __builtin_amdgcn_mfma_f32_16x16x32_bf16(af[ht], bf[vti], oacc[ht][vti], 0, 0, 0);
  }

  // phase F: write per-chunk partials (bf16 o, f32 max/sumexp)
  const float* vnew = q + (size_t)(33 * 32 + b) * 128;
#pragma unroll
  for (int ht = 0; ht < 2; ++ht)
#pragma unroll
    for (int vti = 0; vti < 2; ++vti) {
      int v = w * 32 + vti * 16 + l15;
#pragma unroll
      for (int i = 0; i < 4; ++i) {
        int h = ht * 16 + lg * 4 + i;
        float val = oacc[ht][vti][i];
        if (c == 63) val += sextra[h] * vnew[v];
        apo[((size_t)(b * 64 + c) * 32 + h) * 128 + v] = f2bf(val);
      }
    }
  if (tid < 32) {
    size_t base = ((size_t)(b * 64 + c) * 32 + tid) * 2;
    msum[base]     = smax[tid];
    msum[base + 1] = ssum[tid];
  }
}

// ---------------- kernel 4: combine chunk partials -> o[b][h][v]
// Rewritten: 256 threads/block, 4 waves each own 16 chunks, coalesced u32 loads,
// LDS cross-wave reduce. (Old 2-wave serial-strided version was latency-bound.)
__global__ __launch_bounds__(256) void k_combine(const unsigned short* __restrict__ apo,
    const float* __restrict__ msum, float* __restrict__ o)
{
  __shared__ float redN[4][128];
  __shared__ float redD[4];
  int bid = blockIdx.x;            // 1024: b*32+h
  int b = bid >> 5, h = bid & 31;
  int tid = threadIdx.x, w = tid >> 6, l = tid & 63;

  // global max over 64 chunk maxima (all waves redundantly; no sync needed)
  float gm = msum[((size_t)(b * 64 + l) * 32 + h) * 2];
#pragma unroll
  for (int d = 1; d < 64; d <<= 1) gm = fmaxf(gm, __shfl_xor(gm, d));

  float num0 = 0.f, num1 = 0.f, den = 0.f;
#pragma unroll 4
  for (int i = 0; i < 16; ++i) {
    int cc = w * 16 + i;
    size_t slot = (size_t)(b * 64 + cc) * 32 + h;
    float sc = __expf(msum[slot * 2] - gm);
    den += sc * msum[slot * 2 + 1];
    unsigned pp = *(const unsigned*)&apo[slot * 128 + l * 2];
    num0 += sc * bf2f((unsigned short)(pp & 0xFFFFu));
    num1 += sc * bf2f((unsigned short)(pp >> 16));
  }
  redN[w][l * 2] = num0;
  redN[w][l * 2 + 1] = num1;
  if (l == 0) redD[w] = den;
  __syncthreads();
  if (tid < 128) {
    float num = redN[0][tid] + redN[1][tid] + redN[2][tid] + redN[3][tid];
    float dd  = redD[0] + redD[1] + redD[2] + redD[3];
    o[((size_t)(b * 32 + h)) * 128 + tid] = num / dd;
  }
}

// ---------------- kernel 5: y partials = o x P_o  (grid 512 = 64 d-tiles x 8 head-groups)
__global__ __launch_bounds__(256) void k_out(const float* __restrict__ o,
    const float* __restrict__ Po, float* __restrict__ ypart)
{
  int bid = blockIdx.x;
  int dt = bid >> 3, hg = bid & 7;
  int tid = threadIdx.x, w = tid >> 6, l = tid & 63, l15 = l & 15, lg = l >> 4;
  int d = dt * 64 + w * 16 + l15;
  f32x4 acc[2] = {};               // [b-tile]
  for (int hi = 0; hi < 4; ++hi) {
    int h = hg * 4 + hi;
#pragma unroll
    for (int ks = 0; ks < 4; ++ks) {
      short8 af[2];
#pragma unroll
      for (int bt = 0; bt < 2; ++bt)
        af[bt] = load8cvt(o + ((size_t)((bt * 16 + l15) * 32 + h)) * 128 + ks * 32 + lg * 8);
      short8 bf = load8cvt(Po + ((size_t)h * D_ + d) * 128 + ks * 32 + lg * 8);
#pragma unroll
      for (int bt = 0; bt < 2; ++bt)
        acc[bt] = __builtin_amdgcn_mfma_f32_16x16x32_bf16(af[bt], bf, acc[bt], 0, 0, 0);
    }
  }
#pragma unroll
  for (int bt = 0; bt < 2; ++bt)
#pragma unroll
    for (int i = 0; i < 4; ++i) {
      int b = bt * 16 + lg * 4 + i;
      ypart[((size_t)(hg * 32 + b)) * 4096 + d] = acc[bt][i];
    }
}

// ---------------- kernel 6: reduce y partials -> y
__global__ __launch_bounds__(256) void k_reduce_y(const float* __restrict__ ypart,
    float* __restrict__ dout)
{
  int idx = blockIdx.x * 256 + threadIdx.x;  // 131072
  float s = 0.f;
#pragma unroll
  for (int g = 0; g < 8; ++g) s += ypart[(size_t)g * 131072 + idx];
  dout[idx] = s;
}

extern "C" void kernel_launch(void* const* d_in, const int* in_sizes, int n_in,
                              void* d_out, int out_size, void* d_ws, size_t ws_size,
                              hipStream_t stream) {
  (void)in_sizes; (void)n_in; (void)out_size; (void)ws_size;
  const float* x  = (const float*)d_in[0];
  const float* Kp = (const float*)d_in[1];
  const float* Vp = (const float*)d_in[2];
  const float* Pq = (const float*)d_in[3];
  const float* Pk = (const float*)d_in[4];
  const float* Pv = (const float*)d_in[5];
  const float* Po = (const float*)d_in[6];
  float* out = (float*)d_out;
  float* ws  = (float*)d_ws;
  float* q     = ws + Q_OFF;
  float* o     = ws + O_OFF;
  float* ypart = ws + YPART_OFF;
  float* qpart = ws + QPART_OFF;
  unsigned short* apo = (unsigned short*)(ws + APO_OFF);
  float* msum  = ws + MSUM_OFF;

  hipLaunchKernelGGL(k_proj,     dim3(544),  dim3(256), 0, stream, x, Pq, Pk, Pv, qpart);
  hipLaunchKernelGGL(k_reduce_q, dim3(544),  dim3(256), 0, stream, qpart, q, out);
  hipLaunchKernelGGL(k_attn,     dim3(2048), dim3(256), 0, stream, Kp, Vp, q, out, apo, msum);
  hipLaunchKernelGGL(k_combine,  dim3(1024), dim3(256), 0, stream, apo, msum, o);
  hipLaunchKernelGGL(k_out,      dim3(512),  dim3(256), 0, stream, o, Po, ypart);
  hipLaunchKernelGGL(k_reduce_y, dim3(512),  dim3(256), 0, stream, ypart, out);
}